// Round 7
// baseline (2836.019 us; speedup 1.0000x reference)
//
#include <hip/hip_runtime.h>
#include <hip/hip_bf16.h>
#include <math.h>

// ---------------------------------------------------------------------------
// GPT-style transformer forward. Round 7: global_load_lds 2-phase GEMMs.
// L=4, H=12, HD=64, D=768, V=50257, B=1, T=2048
// Round-6 profile: k_mm still latency-bound (MfmaUtil 13.7%, VALU 24%, HBM
// 25%, occ 33%) -- reg-staging kept loads->VGPR->convert->ds_write on the
// critical path. Layer GEMMs ~420us/layer = the dominant cost.
// Fix (guide T3-minimum, m97/m193/m230): k_mm_bf stages A and B straight to
// LDS with width-16 global_load_lds (wave w owns kslot-plane w; plane rows
// are contiguous so DMA lane*16 matches the layout), one barrier per K-step.
// LM head (fp32 B) hybrid: A via global_load_lds, B reg-staged by all 256
// threads, stored after the MFMAs.
// ---------------------------------------------------------------------------

typedef __attribute__((ext_vector_type(8))) short bf16x8;
typedef __attribute__((ext_vector_type(4))) float f32x4;
typedef unsigned short u16;

// bf16 weight-pool layout (elems per layer): [qkv 2304x768][o 768x768]
// [w1 3072x768][w2 768x3072]
constexpr int OSZ   = 589824;        // 768*768
constexpr int QKVSZ = 3 * OSZ;       // 1769472
constexpr int W1SZ  = 2359296;       // 3072*768
constexpr int PER_L = QKVSZ + OSZ + W1SZ + W1SZ;  // 7077888

__device__ __forceinline__ u16 f2bf(float f) {
  unsigned u = __float_as_uint(f);
  u += 0x7FFFu + ((u >> 16) & 1u);
  return (u16)(u >> 16);
}

__device__ __forceinline__ float gelu_exact(float v) {
  return 0.5f * v * (1.0f + erff(v * 0.70710678118654752f));
}

// async global->LDS, 16 B per lane: LDS dest = uniform base + lane*16,
// global src per-lane. Counted by vmcnt; __syncthreads() drains it.
__device__ __forceinline__ void gload16(const void* g, void* l) {
  __builtin_amdgcn_global_load_lds(
      (const __attribute__((address_space(1))) unsigned int*)g,
      (__attribute__((address_space(3))) unsigned int*)l, 16, 0, 0);
}

// Bijective XCD swizzle (m204): contiguous logical chunk per XCD.
__device__ __forceinline__ int xcd_swizzle(int orig, int nwg) {
  int xcd = orig & 7, lid = orig >> 3;
  int q8 = nwg >> 3, r8 = nwg & 7;
  return (xcd < r8 ? xcd * (q8 + 1) : r8 * (q8 + 1) + (xcd - r8) * q8) + lid;
}

__global__ __launch_bounds__(256) void k_embed(const int* __restrict__ ids,
                                               const float* __restrict__ emb,
                                               float* __restrict__ x,
                                               int T, int D) {
  int t = blockIdx.x;
  int id = ids[t];
  float neg_log = -logf(10000.0f) / (float)D;
  for (int d = threadIdx.x; d < D; d += 256) {
    float freq = expf((float)(d & ~1) * neg_log);
    float ang = (float)t * freq;
    float pe = (d & 1) ? cosf(ang) : sinf(ang);
    x[(size_t)t * D + d] = emb[(size_t)id * D + d] + pe;
  }
}

// LayerNorm, bf16 output (same rounding the consumer GEMM applied before).
__global__ __launch_bounds__(256) void k_layernorm(const float* __restrict__ x,
                                                   const float* __restrict__ g,
                                                   const float* __restrict__ b,
                                                   u16* __restrict__ y,
                                                   int D) {
  int t = blockIdx.x;
  const float* xr = x + (size_t)t * D;
  __shared__ float red[256];
  float s = 0.f;
  for (int d = threadIdx.x; d < D; d += 256) s += xr[d];
  red[threadIdx.x] = s;
  __syncthreads();
  for (int st = 128; st > 0; st >>= 1) {
    if (threadIdx.x < st) red[threadIdx.x] += red[threadIdx.x + st];
    __syncthreads();
  }
  float mean = red[0] / (float)D;
  __syncthreads();
  float s2 = 0.f;
  for (int d = threadIdx.x; d < D; d += 256) {
    float u = xr[d] - mean;
    s2 += u * u;
  }
  red[threadIdx.x] = s2;
  __syncthreads();
  for (int st = 128; st > 0; st >>= 1) {
    if (threadIdx.x < st) red[threadIdx.x] += red[threadIdx.x + st];
    __syncthreads();
  }
  float rstd = rsqrtf(red[0] / (float)D + 1e-5f);
  u16* yr = y + (size_t)t * D;
  for (int d = threadIdx.x; d < D; d += 256)
    yr[d] = f2bf((xr[d] - mean) * rstd * g[d] + b[d]);
}

// One-time weight cast: fp32 inputs -> bf16 pool (layout above). 8 elems/thr.
__global__ __launch_bounds__(256) void k_castw(const float* __restrict__ Wq,
                                               const float* __restrict__ Wk,
                                               const float* __restrict__ Wv,
                                               const float* __restrict__ Wo,
                                               const float* __restrict__ W1,
                                               const float* __restrict__ W2,
                                               u16* __restrict__ pool) {
  unsigned i8 = (blockIdx.x * 256u + threadIdx.x) * 8u;
  unsigned l = i8 / (unsigned)PER_L;
  unsigned off = i8 - l * (unsigned)PER_L;
  const float* src;
  if (off < (unsigned)QKVSZ) {
    unsigned w = off / (unsigned)OSZ;
    unsigned o = off - w * (unsigned)OSZ;
    src = (w == 0 ? Wq : (w == 1 ? Wk : Wv)) + (size_t)l * OSZ + o;
  } else if (off < (unsigned)(QKVSZ + OSZ)) {
    src = Wo + (size_t)l * OSZ + (off - QKVSZ);
  } else if (off < (unsigned)(QKVSZ + OSZ + W1SZ)) {
    src = W1 + (size_t)l * W1SZ + (off - (QKVSZ + OSZ));
  } else {
    src = W2 + (size_t)l * W1SZ + (off - (QKVSZ + OSZ + W1SZ));
  }
  float4 a = *(const float4*)src;
  float4 b = *(const float4*)(src + 4);
  union { bf16x8 v; u16 u[8]; } r;
  r.u[0] = f2bf(a.x); r.u[1] = f2bf(a.y); r.u[2] = f2bf(a.z); r.u[3] = f2bf(a.w);
  r.u[4] = f2bf(b.x); r.u[5] = f2bf(b.y); r.u[6] = f2bf(b.z); r.u[7] = f2bf(b.w);
  *(bf16x8*)(pool + i8) = r.v;
}

// Concatenated QKV bias.
__global__ __launch_bounds__(256) void k_castb(const float* __restrict__ bq,
                                               const float* __restrict__ bk,
                                               const float* __restrict__ bv,
                                               float* __restrict__ bqkv) {
  for (int i = threadIdx.x; i < 4 * 2304; i += 256) {
    int l = i / 2304, c = i - l * 2304;
    int w = c / 768, cc = c - w * 768;
    bqkv[i] = (w == 0 ? bq : (w == 1 ? bk : bv))[l * 768 + cc];
  }
}

// ---------------------------------------------------------------------------
// k_mm_bf: C[M,N] = A[M,K](bf16) @ B[N,K](bf16)^T + bias[N]
// mode 0: bias, fp32 C; mode 1: bias+res, fp32 C; mode 2: gelu, bf16 C.
// Requires M%128==0, N%128==0, K%32==0 (all layer GEMMs qualify).
// 128x128 tile, BK=32, 4 waves (64x64 quadrant each), mfma 16x16x32 bf16.
// 2-phase global_load_lds pipeline: wave w stages kslot-plane w of A and B
// (2x 1024B insts each; plane rows contiguous so lane*16 lands on row lane),
// then ds_read + 16 MFMA on buf[cur], then one __syncthreads() (drains vmcnt)
// per K-step. Loads for kt+1 stay in flight across the MFMA phase.
// ---------------------------------------------------------------------------
__global__ __launch_bounds__(256) void k_mm_bf(const u16* __restrict__ A,
                                               const u16* __restrict__ B,
                                               const float* __restrict__ bias,
                                               const float* __restrict__ res,
                                               void* __restrict__ Cv,
                                               int M, int N, int K, int mode) {
  constexpr int PLANE = 2080;      // 128 rows * 16 B + 32 pad
  constexpr int MATS  = 4 * PLANE; // per matrix per buffer
  constexpr int BUFSZ = 2 * MATS;  // A+B per buffer (16640 B)
  __shared__ alignas(16) unsigned char smem[2 * BUFSZ];

  const int nbx = N >> 7;
  const int nby = M >> 7;
  const int swz = xcd_swizzle(blockIdx.x, nbx * nby);
  const int nb = swz / nby;        // n panel major
  const int mb = swz - nb * nby;   // m fastest
  const int m0 = mb << 7, n0 = nb << 7;

  const int tid = threadIdx.x;
  const int lane = tid & 63;
  const int w = tid >> 6;          // wave id = kslot this wave stages
  const int wr = w >> 1, wc = w & 1;

  // per-lane global row bases for this wave's kslot plane (k offset w*8)
  const u16* Ar0 = A + (size_t)(m0 + lane) * K + (w << 3);
  const u16* Ar1 = A + (size_t)(m0 + 64 + lane) * K + (w << 3);
  const u16* Br0 = B + (size_t)(n0 + lane) * K + (w << 3);
  const u16* Br1 = B + (size_t)(n0 + 64 + lane) * K + (w << 3);

  const int lr = lane & 15, lk = lane >> 4;
  const int ardo = lk * PLANE + (wr * 64 + lr) * 16;
  const int brdo = MATS + lk * PLANE + (wc * 64 + lr) * 16;

  f32x4 acc[4][4] = {};
  const int NK = K >> 5;

  auto STAGE = [&](int buf, int kt) {
    const int ko = kt << 5;
    unsigned char* la = smem + buf * BUFSZ + w * PLANE;
    unsigned char* lb = la + MATS;
    gload16(Ar0 + ko, la);
    gload16(Ar1 + ko, la + 1024);
    gload16(Br0 + ko, lb);
    gload16(Br1 + ko, lb + 1024);
  };

  STAGE(0, 0);
  __syncthreads();
  int cur = 0;

  for (int kt = 0; kt < NK; ++kt) {
    if (kt + 1 < NK) STAGE(cur ^ 1, kt + 1);
    const unsigned char* base = smem + cur * BUFSZ;
    bf16x8 af[4], bfr[4];
#pragma unroll
    for (int f = 0; f < 4; ++f) {
      af[f]  = *(const bf16x8*)(base + ardo + f * 256);
      bfr[f] = *(const bf16x8*)(base + brdo + f * 256);
    }
#pragma unroll
    for (int fm = 0; fm < 4; ++fm)
#pragma unroll
      for (int fn = 0; fn < 4; ++fn)
        acc[fm][fn] = __builtin_amdgcn_mfma_f32_16x16x32_bf16(
            af[fm], bfr[fn], acc[fm][fn], 0, 0, 0);
    __syncthreads();   // drains vmcnt(0): buf[cur^1] staged, all reads done
    cur ^= 1;
  }

  const int orow0 = m0 + wr * 64 + (lk << 2);
  const int ocol0 = n0 + wc * 64 + lr;
  if (mode == 2) {
    u16* C = (u16*)Cv;
#pragma unroll
    for (int fn = 0; fn < 4; ++fn) {
      int col = ocol0 + fn * 16;
      float bv = bias[col];
#pragma unroll
      for (int fm = 0; fm < 4; ++fm)
#pragma unroll
        for (int j = 0; j < 4; ++j) {
          int row = orow0 + fm * 16 + j;
          C[(size_t)row * N + col] = f2bf(gelu_exact(acc[fm][fn][j] + bv));
        }
    }
  } else {
    float* C = (float*)Cv;
#pragma unroll
    for (int fn = 0; fn < 4; ++fn) {
      int col = ocol0 + fn * 16;
      float bv = bias[col];
#pragma unroll
      for (int fm = 0; fm < 4; ++fm)
#pragma unroll
        for (int j = 0; j < 4; ++j) {
          int row = orow0 + fm * 16 + j;
          float vvv = acc[fm][fn][j] + bv;
          if (mode == 1) vvv += res[(size_t)row * N + col];
          C[(size_t)row * N + col] = vvv;
        }
    }
  }
}

// ---------------------------------------------------------------------------
// k_mm_lmh: LM head. C[M,N] = A[M,K](bf16) @ B[N,K](fp32->bf16)^T + bias.
// A staged via global_load_lds (as k_mm_bf); B reg-staged by all 256 threads
// (thread = row tid>>1, k-half tid&1: 4x float4 -> 2x bf16x8 ds_write), with
// the LDS store issued AFTER the MFMAs so load latency hides under compute.
// B rows clamped to N-1 (garbage cols never stored: epilogue guards col<N).
// ---------------------------------------------------------------------------
__global__ __launch_bounds__(256) void k_mm_lmh(const u16* __restrict__ A,
                                                const float* __restrict__ B,
                                                const float* __restrict__ bias,
                                                float* __restrict__ C,
                                                int M, int N, int K) {
  constexpr int PLANE = 2080;
  constexpr int MATS  = 4 * PLANE;
  constexpr int BUFSZ = 2 * MATS;
  __shared__ alignas(16) unsigned char smem[2 * BUFSZ];

  const int nbx = (N + 127) >> 7;
  const int nby = M >> 7;
  const int swz = xcd_swizzle(blockIdx.x, nbx * nby);
  const int nb = swz / nby;
  const int mb = swz - nb * nby;
  const int m0 = mb << 7, n0 = nb << 7;

  const int tid = threadIdx.x;
  const int lane = tid & 63;
  const int w = tid >> 6;
  const int wr = w >> 1, wc = w & 1;

  const u16* Ar0 = A + (size_t)(m0 + lane) * K + (w << 3);
  const u16* Ar1 = A + (size_t)(m0 + 64 + lane) * K + (w << 3);

  // B staging role: row br, k-half bh (16 floats = planes 2bh, 2bh+1)
  const int br = tid >> 1, bh = tid & 1;
  const int brow = min(n0 + br, N - 1);
  const float* Bp = B + (size_t)brow * K + (bh << 4);

  const int lr = lane & 15, lk = lane >> 4;
  const int ardo = lk * PLANE + (wr * 64 + lr) * 16;
  const int brdo = MATS + lk * PLANE + (wc * 64 + lr) * 16;

  f32x4 acc[4][4] = {};
  float4 rb[4];
  const int NK = K >> 5;

  auto STAGE_A = [&](int buf, int kt) {
    unsigned char* la = smem + buf * BUFSZ + w * PLANE;
    gload16(Ar0 + (kt << 5), la);
    gload16(Ar1 + (kt << 5), la + 1024);
  };
  auto LOADB = [&](int kt) {
    const float* p = Bp + (kt << 5);
#pragma unroll
    for (int i = 0; i < 4; ++i) rb[i] = *(const float4*)(p + (i << 2));
  };
  auto STOREB = [&](int buf) {
    union { bf16x8 v; u16 u[8]; } r0, r1;
    r0.u[0] = f2bf(rb[0].x); r0.u[1] = f2bf(rb[0].y);
    r0.u[2] = f2bf(rb[0].z); r0.u[3] = f2bf(rb[0].w);
    r0.u[4] = f2bf(rb[1].x); r0.u[5] = f2bf(rb[1].y);
    r0.u[6] = f2bf(rb[1].z); r0.u[7] = f2bf(rb[1].w);
    r1.u[0] = f2bf(rb[2].x); r1.u[1] = f2bf(rb[2].y);
    r1.u[2] = f2bf(rb[2].z); r1.u[3] = f2bf(rb[2].w);
    r1.u[4] = f2bf(rb[3].x); r1.u[5] = f2bf(rb[3].y);
    r1.u[6] = f2bf(rb[3].z); r1.u[7] = f2bf(rb[3].w);
    unsigned char* wb = smem + buf * BUFSZ + MATS;
    *(bf16x8*)(wb + (2 * bh)     * PLANE + br * 16) = r0.v;
    *(bf16x8*)(wb + (2 * bh + 1) * PLANE + br * 16) = r1.v;
  };

  LOADB(0);
  STAGE_A(0, 0);
  STOREB(0);
  __syncthreads();
  int cur = 0;

  for (int kt = 0; kt < NK; ++kt) {
    if (kt + 1 < NK) {
      LOADB(kt + 1);
      STAGE_A(cur ^ 1, kt + 1);
    }
    const unsigned char* base = smem + cur * BUFSZ;
    bf16x8 af[4], bfr[4];
#pragma unroll
    for (int f = 0; f < 4; ++f) {
      af[f]  = *(const bf16x8*)(base + ardo + f * 256);
      bfr[f] = *(const bf16x8*)(base + brdo + f * 256);
    }
#pragma unroll
    for (int fm = 0; fm < 4; ++fm)
#pragma unroll
      for (int fn = 0; fn < 4; ++fn)
        acc[fm][fn] = __builtin_amdgcn_mfma_f32_16x16x32_bf16(
            af[fm], bfr[fn], acc[fm][fn], 0, 0, 0);
    if (kt + 1 < NK) STOREB(cur ^ 1);  // vmcnt wait lands here, after MFMAs
    __syncthreads();
    cur ^= 1;
  }

  const int orow0 = m0 + wr * 64 + (lk << 2);
  const int ocol0 = n0 + wc * 64 + lr;
#pragma unroll
  for (int fn = 0; fn < 4; ++fn) {
    int col = ocol0 + fn * 16;
    if (col >= N) continue;
    float bv = bias[col];
#pragma unroll
    for (int fm = 0; fm < 4; ++fm)
#pragma unroll
      for (int j = 0; j < 4; ++j) {
        int row = orow0 + fm * 16 + j;
        C[(size_t)row * N + col] = acc[fm][fn][j] + bv;
      }
  }
}

// ---------------------------------------------------------------------------
// Tiled flash attention (fp32 VALU) — unchanged from round 6.
// ---------------------------------------------------------------------------
__global__ __launch_bounds__(256) void k_flash(const float* __restrict__ q,
                                               const float* __restrict__ k,
                                               const float* __restrict__ v,
                                               u16* __restrict__ ctx,
                                               int T, int QS, int D,
                                               float scale) {
  __shared__ float Qs[64][68];
  __shared__ float KPs[64][68];
  __shared__ float Vs[64][68];
  int tid = threadIdx.x;
  int tx = tid & 15, ty = tid >> 4;
  int qt = gridDim.x - 1 - blockIdx.x;
  int q0 = qt << 6;
  int hoff = blockIdx.y << 6;

  {
    int row = tid >> 2;
    int col = (tid & 3) << 4;
    const float* src = q + (size_t)(q0 + row) * QS + hoff + col;
#pragma unroll
    for (int i = 0; i < 4; ++i) {
      float4 a = *(const float4*)(src + (i << 2));
      Qs[col + (i << 2) + 0][row] = a.x * scale;
      Qs[col + (i << 2) + 1][row] = a.y * scale;
      Qs[col + (i << 2) + 2][row] = a.z * scale;
      Qs[col + (i << 2) + 3][row] = a.w * scale;
    }
  }

  float m[4] = {-1e30f, -1e30f, -1e30f, -1e30f};
  float l[4] = {0.f, 0.f, 0.f, 0.f};
  float po[4][4] = {};

  for (int st = 0; st <= qt; ++st) {
    int s0 = st << 6;
    __syncthreads();
    {
      int row = tid >> 2;
      int col = (tid & 3) << 4;
      const float* ksrc = k + (size_t)(s0 + row) * QS + hoff + col;
      const float* vsrc = v + (size_t)(s0 + row) * QS + hoff + col;
#pragma unroll
      for (int i = 0; i < 4; ++i) {
        float4 a = *(const float4*)(ksrc + (i << 2));
        KPs[col + (i << 2) + 0][row] = a.x;
        KPs[col + (i << 2) + 1][row] = a.y;
        KPs[col + (i << 2) + 2][row] = a.z;
        KPs[col + (i << 2) + 3][row] = a.w;
        *(float4*)&Vs[row][col + (i << 2)] = *(const float4*)(vsrc + (i << 2));
      }
    }
    __syncthreads();

    float s[4][4] = {};
#pragma unroll 8
    for (int kk = 0; kk < 64; ++kk) {
      float4 a = *(const float4*)&Qs[kk][ty << 2];
      float4 b = *(const float4*)&KPs[kk][tx << 2];
      s[0][0] += a.x * b.x; s[0][1] += a.x * b.y; s[0][2] += a.x * b.z; s[0][3] += a.x * b.w;
      s[1][0] += a.y * b.x; s[1][1] += a.y * b.y; s[1][2] += a.y * b.z; s[1][3] += a.y * b.w;
      s[2][0] += a.z * b.x; s[2][1] += a.z * b.y; s[2][2] += a.z * b.z; s[2][3] += a.z * b.w;
      s[3][0] += a.w * b.x; s[3][1] += a.w * b.y; s[3][2] += a.w * b.z; s[3][3] += a.w * b.w;
    }

    if (st == qt) {
#pragma unroll
      for (int qi = 0; qi < 4; ++qi) {
        int qrow = (ty << 2) + qi;
#pragma unroll
        for (int si = 0; si < 4; ++si) {
          if ((tx << 2) + si > qrow) s[qi][si] = -1e30f;
        }
      }
    }

    float alpha[4];
#pragma unroll
    for (int qi = 0; qi < 4; ++qi) {
      float rmax = fmaxf(fmaxf(s[qi][0], s[qi][1]), fmaxf(s[qi][2], s[qi][3]));
      rmax = fmaxf(rmax, __shfl_xor(rmax, 1, 64));
      rmax = fmaxf(rmax, __shfl_xor(rmax, 2, 64));
      rmax = fmaxf(rmax, __shfl_xor(rmax, 4, 64));
      rmax = fmaxf(rmax, __shfl_xor(rmax, 8, 64));
      float mn = fmaxf(m[qi], rmax);
      alpha[qi] = __expf(m[qi] - mn);
      m[qi] = mn;
      float rsum = 0.f;
#pragma unroll
      for (int si = 0; si < 4; ++si) {
        float p = __expf(s[qi][si] - mn);
        s[qi][si] = p;
        rsum += p;
      }
      rsum += __shfl_xor(rsum, 1, 64);
      rsum += __shfl_xor(rsum, 2, 64);
      rsum += __shfl_xor(rsum, 4, 64);
      rsum += __shfl_xor(rsum, 8, 64);
      l[qi] = l[qi] * alpha[qi] + rsum;
      po[qi][0] *= alpha[qi]; po[qi][1] *= alpha[qi];
      po[qi][2] *= alpha[qi]; po[qi][3] *= alpha[qi];
    }

    __syncthreads();
#pragma unroll
    for (int si = 0; si < 4; ++si) {
      float4 p4 = make_float4(s[0][si], s[1][si], s[2][si], s[3][si]);
      *(float4*)&KPs[(tx << 2) + si][ty << 2] = p4;
    }
    __syncthreads();

#pragma unroll 8
    for (int kk = 0; kk < 64; ++kk) {
      float4 a = *(const float4*)&KPs[kk][ty << 2];
      float4 b = *(const float4*)&Vs[kk][tx << 2];
      po[0][0] += a.x * b.x; po[0][1] += a.x * b.y; po[0][2] += a.x * b.z; po[0][3] += a.x * b.w;
      po[1][0] += a.y * b.x; po[1][1] += a.y * b.y; po[1][2] += a.y * b.z; po[1][3] += a.y * b.w;
      po[2][0] += a.z * b.x; po[2][1] += a.z * b.y; po[2][2] += a.z * b.z; po[2][3] += a.z * b.w;
      po[3][0] += a.w * b.x; po[3][1] += a.w * b.y; po[3][2] += a.w * b.z; po[3][3] += a.w * b.w;
    }
  }

#pragma unroll
  for (int qi = 0; qi < 4; ++qi) {
    float inv = 1.0f / l[qi];
    ushort4 r;
    r.x = f2bf(po[qi][0] * inv); r.y = f2bf(po[qi][1] * inv);
    r.z = f2bf(po[qi][2] * inv); r.w = f2bf(po[qi][3] * inv);
    *(ushort4*)(ctx + (size_t)(q0 + (ty << 2) + qi) * D + hoff + (tx << 2)) = r;
  }
}

extern "C" void kernel_launch(void* const* d_in, const int* in_sizes, int n_in,
                              void* d_out, int out_size, void* d_ws, size_t ws_size,
                              hipStream_t stream) {
  const int T = 2048, D = 768, H = 12, L = 4, V = 50257, D4 = 3072;
  const size_t td = (size_t)T * D;

  const int* ids      = (const int*)d_in[0];
  const float* emb    = (const float*)d_in[1];
  const float* lm_bias= (const float*)d_in[2];
  const float* ln1_g  = (const float*)d_in[3];
  const float* ln1_b  = (const float*)d_in[4];
  const float* ln2_g  = (const float*)d_in[5];
  const float* ln2_b  = (const float*)d_in[6];
  const float* Wq     = (const float*)d_in[7];
  const float* bq     = (const float*)d_in[8];
  const float* Wk     = (const float*)d_in[9];
  const float* bk     = (const float*)d_in[10];
  const float* Wv     = (const float*)d_in[11];
  const float* bv     = (const float*)d_in[12];
  const float* Wo     = (const float*)d_in[13];
  const float* bo     = (const float*)d_in[14];
  const float* W1     = (const float*)d_in[15];
  const float* b1     = (const float*)d_in[16];
  const float* W2     = (const float*)d_in[17];
  const float* b2     = (const float*)d_in[18];
  const float* lnf_g  = (const float*)d_in[19];
  const float* lnf_b  = (const float*)d_in[20];
  float* out = (float*)d_out;

  // Scratch (same as round 6):
  //   d_ws: x fp32 [T,768] + xnb bf16 [T,768] (9.4 MB).
  //   d_out front (~91 MB), all dead before the LM-head GEMM:
  //     wpool bf16 (56.6 MB) | bqkv fp32 | qkv fp32 [T,2304] |
  //     cbb bf16 [T,768] | hbb bf16 [T,3072]
  float* x  = (float*)d_ws;
  u16* xnb  = (u16*)(x + td);

  char* cur = (char*)d_out;
  u16* wpool = (u16*)cur;  cur += (size_t)4 * PER_L * 2;
  float* bqkv = (float*)cur; cur += (size_t)4 * 2304 * 4;
  float* qkv = (float*)cur;  cur += (size_t)3 * td * 4;
  u16* cbb = (u16*)cur;      cur += td * 2;
  u16* hbb = (u16*)cur;

  dim3 blk(256);

  k_castw<<<(4 * PER_L) / (256 * 8), blk, 0, stream>>>(Wq, Wk, Wv, Wo, W1, W2, wpool);
  k_castb<<<1, blk, 0, stream>>>(bq, bk, bv, bqkv);

  k_embed<<<T, blk, 0, stream>>>(ids, emb, x, T, D);

  for (int l = 0; l < L; ++l) {
    const u16* wl = wpool + (size_t)l * PER_L;

    k_layernorm<<<T, blk, 0, stream>>>(x, ln1_g + l * D, ln1_b + l * D, xnb, D);

    k_mm_bf<<<18 * 16, blk, 0, stream>>>(xnb, wl, bqkv + l * 2304, nullptr,
                                         qkv, T, 2304, 768, 0);

    dim3 ga(T / 64, H);
    k_flash<<<ga, blk, 0, stream>>>(qkv, qkv + 768, qkv + 1536, cbb,
                                    T, 2304, D, 0.125f);

    k_mm_bf<<<6 * 16, blk, 0, stream>>>(cbb, wl + QKVSZ, bo + l * D, x,
                                        x, T, 768, 768, 1);

    k_layernorm<<<T, blk, 0, stream>>>(x, ln2_g + l * D, ln2_b + l * D, xnb, D);

    k_mm_bf<<<24 * 16, blk, 0, stream>>>(xnb, wl + QKVSZ + OSZ, b1 + l * D4, nullptr,
                                         hbb, T, 3072, 768, 2);

    k_mm_bf<<<6 * 16, blk, 0, stream>>>(hbb, wl + QKVSZ + OSZ + W1SZ, b2 + l * D, x,
                                        x, T, 768, 3072, 1);
  }

  k_layernorm<<<T, blk, 0, stream>>>(x, lnf_g, lnf_b, xnb, D);

  k_mm_lmh<<<((V + 127) / 128) * 16, blk, 0, stream>>>(xnb, emb, lm_bias,
                                                       out, T, V, 768);
}